// Round 3
// baseline (354.863 us; speedup 1.0000x reference)
//
#include <hip/hip_runtime.h>
#include <math.h>

#define EPSF 2.2e-10f
#define NV 30000
#define NB 512

typedef __attribute__((ext_vector_type(8))) short short8;
typedef __attribute__((ext_vector_type(4))) float f32x4;
typedef __attribute__((ext_vector_type(4))) unsigned short ushort4v;

__device__ __forceinline__ unsigned short f2bf(float f) {
    unsigned int u = __float_as_uint(f);
    u += 0x7fffu + ((u >> 16) & 1u);
    return (unsigned short)(u >> 16);
}
__device__ __forceinline__ float bf2f(unsigned short h) {
    return __uint_as_float((unsigned int)h << 16);
}

// ---------------------------------------------------------------- digamma
__device__ __forceinline__ float digammaf(float xx) {
    float x = xx, r = 0.f;
    while (x < 6.f) { r -= 1.f / x; x += 1.f; }
    float f = 1.f / (x * x);
    float s = logf(x) - 0.5f / x
        - f * (0.0833333333f - f * (0.0083333333f - f * (0.0039682540f
        - f * (0.0041666667f - f * 0.0075757576f))));
    return r + s;
}

// ================================================================ pk_theta
// theta0 (128,512) f32 -> th_bf (128,512) bf16 and thT_bf (512,128) bf16
__global__ __launch_bounds__(256) void pk_theta(
    const float* __restrict__ th, unsigned short* __restrict__ th_bf,
    unsigned short* __restrict__ thT_bf)
{
    int idx = blockIdx.x * 256 + threadIdx.x;   // 16384 threads
    int k = idx >> 7, b4 = (idx & 127) << 2;
    float4 v = *(const float4*)&th[k * NB + b4];
    ushort4v h = { f2bf(v.x), f2bf(v.y), f2bf(v.z), f2bf(v.w) };
    *(ushort4v*)&th_bf[k * NB + b4] = h;
#pragma unroll
    for (int i = 0; i < 4; ++i) thT_bf[(b4 + i) * 128 + k] = h[i];
}

// ================================================================ k1 (MFMA)
// Per block: 32 v-rows, 8 b-chunks of 64.
//  denomT(b,v) = thetaT(b,:)@phiT(:,v)  [MFMA, A from global thT_bf]
//  ratioT(b,v) = x/denom -> bf16 -> LDS rat_vb + DIRECT global stores
//  R0T(k,v)   += theta(k,:)@ratioT(:,v) [MFMA, A from global th_bf]
// Also writes phiT (bf16 k-major) for k2. NDot from registers.
#define PHI_VK(v,k) (((((v) << 8) + ((k) << 1))) ^ (((v) & 7) << 4))
#define RAT_VB(v,b) ((8192 + (((v) << 7) + ((b) << 1))) ^ (((v) & 7) << 4))
#define R0S(v,k)    (((((v) << 9) + ((k) << 2))) ^ (((v) & 7) << 4))

__global__ __launch_bounds__(256, 4) void k1_mfma(
    const float* __restrict__ x,              // (B,V)
    const float* __restrict__ phi0,           // (V,128)
    const unsigned short* __restrict__ thT_bf,// (512,128)
    const unsigned short* __restrict__ th_bf, // (128,512)
    unsigned short* __restrict__ ratioT,      // (B,V) bf16
    unsigned short* __restrict__ phiT,        // (128,V) bf16
    float* __restrict__ R0,                   // (V,128) = d_out region
    float* __restrict__ NDot0)                // (128)
{
    __shared__ __align__(16) unsigned char lds[16384];
    const int t = threadIdx.x;
    const int lane = t & 63;
    const int w = t >> 6;
    const int lrow = lane & 15;
    const int lkb = (lane >> 4) << 3;
    const int lcq = (lane >> 4) << 2;
    const int vbase = blockIdx.x * 32;

    // stage phi (32 v-rows) -> bf16 LDS
    for (int idx = t; idx < 512; idx += 256) {
        int v = idx >> 4, kc = (idx & 15) << 3;
        int vg = vbase + v;
        float4 a = {0,0,0,0}, b = {0,0,0,0};
        if (vg < NV) {
            a = *(const float4*)&phi0[vg * 128 + kc];
            b = *(const float4*)&phi0[vg * 128 + kc + 4];
        }
        ushort4v h0 = { f2bf(a.x), f2bf(a.y), f2bf(a.z), f2bf(a.w) };
        ushort4v h1 = { f2bf(b.x), f2bf(b.y), f2bf(b.z), f2bf(b.w) };
        *(ushort4v*)&lds[PHI_VK(v, kc)]     = h0;
        *(ushort4v*)&lds[PHI_VK(v, kc + 4)] = h1;
    }
    __syncthreads();
    // phiT writeout (transpose read from LDS, dense global stores)
    for (int idx = t; idx < 4096; idx += 256) {
        int v = idx & 31, k = idx >> 5;
        int vg = vbase + v;
        if (vg < NV)
            phiT[(size_t)k * NV + vg] = *(const unsigned short*)&lds[PHI_VK(v, k)];
    }

    f32x4 racc[2][2];
#pragma unroll
    for (int tr = 0; tr < 2; ++tr)
#pragma unroll
        for (int j = 0; j < 2; ++j) racc[tr][j] = (f32x4){0.f, 0.f, 0.f, 0.f};

    for (int c = 0; c < 8; ++c) {
        const int b0c = c << 6;
        // x prefetch (8 loads, issued before MFMA chain)
        float xv[2][4];
#pragma unroll
        for (int j = 0; j < 2; ++j) {
            int vg = vbase + j * 16 + lrow;
#pragma unroll
            for (int i = 0; i < 4; ++i) {
                int bg = b0c + w * 16 + lcq + i;
                xv[j][i] = (vg < NV) ? x[(size_t)bg * NV + vg] : 0.f;
            }
        }
        // A-frags (thetaT rows, contraction k) from global (L2-resident)
        short8 at[4];
#pragma unroll
        for (int ks = 0; ks < 4; ++ks)
            at[ks] = *(const short8*)&thT_bf[(size_t)(b0c + w * 16 + lrow) * 128 + ks * 32 + lkb];
        // denom MFMA
        f32x4 dacc[2];
#pragma unroll
        for (int j = 0; j < 2; ++j) dacc[j] = (f32x4){0.f, 0.f, 0.f, 0.f};
#pragma unroll
        for (int ks = 0; ks < 4; ++ks)
#pragma unroll
            for (int j = 0; j < 2; ++j) {
                short8 bf = *(const short8*)&lds[PHI_VK(j * 16 + lrow, ks * 32 + lkb)];
                dacc[j] = __builtin_amdgcn_mfma_f32_16x16x32_bf16(at[ks], bf, dacc[j], 0, 0, 0);
            }
        // ratio = x * rcp(max(denom,eps)); bf16 -> LDS rat_vb + direct global
#pragma unroll
        for (int j = 0; j < 2; ++j) {
            const int vloc = j * 16 + lrow;
            const int vg = vbase + vloc;
            const int bloc = w * 16 + lcq;
            ushort4v h;
#pragma unroll
            for (int i = 0; i < 4; ++i) {
                float den = fmaxf(dacc[j][i], EPSF);
                float r = xv[j][i] * __builtin_amdgcn_rcpf(den);
                h[i] = f2bf(r);
                if (vg < NV) ratioT[(size_t)(b0c + bloc + i) * NV + vg] = h[i];
            }
            *(ushort4v*)&lds[RAT_VB(vloc, bloc)] = h;
        }
        __syncthreads();
        // R0T += theta @ ratioT : A from global th_bf, B from LDS rat_vb
#pragma unroll
        for (int ks = 0; ks < 2; ++ks) {
            short8 bfr[2];
#pragma unroll
            for (int j = 0; j < 2; ++j)
                bfr[j] = *(const short8*)&lds[RAT_VB(j * 16 + lrow, ks * 32 + lkb)];
#pragma unroll
            for (int tr = 0; tr < 2; ++tr) {
                short8 af = *(const short8*)&th_bf[(size_t)(w * 32 + tr * 16 + lrow) * NB + b0c + ks * 32 + lkb];
#pragma unroll
                for (int j = 0; j < 2; ++j)
                    racc[tr][j] = __builtin_amdgcn_mfma_f32_16x16x32_bf16(af, bfr[j], racc[tr][j], 0, 0, 0);
            }
        }
        __syncthreads();
    }

    // NDot0 from registers x phi(LDS): reduce over lrow group, atomic per k
#pragma unroll
    for (int tr = 0; tr < 2; ++tr) {
        float ndp[4] = {0.f, 0.f, 0.f, 0.f};
#pragma unroll
        for (int i = 0; i < 4; ++i)
#pragma unroll
            for (int j = 0; j < 2; ++j) {
                int k = w * 32 + tr * 16 + lcq + i;
                float pv = bf2f(*(const unsigned short*)&lds[PHI_VK(j * 16 + lrow, k)]);
                ndp[i] += pv * racc[tr][j][i];
            }
#pragma unroll
        for (int i = 0; i < 4; ++i) {
            float s = ndp[i];
            s += __shfl_xor(s, 1); s += __shfl_xor(s, 2);
            s += __shfl_xor(s, 4); s += __shfl_xor(s, 8);
            if (lrow == 0) atomicAdd(&NDot0[w * 32 + tr * 16 + lcq + i], 100.f * s);
        }
    }
    __syncthreads();
    // R0 transpose via LDS -> coalesced writeout
#pragma unroll
    for (int tr = 0; tr < 2; ++tr)
#pragma unroll
        for (int j = 0; j < 2; ++j)
            *(f32x4*)&lds[R0S(j * 16 + lrow, w * 32 + tr * 16 + lcq)] = racc[tr][j];
    __syncthreads();
    const int kf = t & 127;
    for (int idx = t; idx < 4096; idx += 256) {
        int v = idx >> 7, vg = vbase + v;
        if (vg < NV) R0[(size_t)vg * 128 + kf] = *(const float*)&lds[R0S(v, kf)];
    }
}

// ================================================================ k2 (MFMA)
// partial[split](k,b) = sum_{v in split} phiT(k,v) * ratio(v,b)
#define PH(k,v)  (((((k) << 7) + ((v) << 1))) ^ (((k) & 7) << 4))
#define RT(b,v)  ((16384 + (((b) << 7) + ((v) << 1))) ^ (((b) & 7) << 4))

__global__ __launch_bounds__(256, 2) void k2_mfma(
    const unsigned short* __restrict__ phiT,   // (128,V) bf16
    const unsigned short* __restrict__ ratioT, // (B,V) bf16
    float* __restrict__ part)                  // (64,128,512) f32
{
    __shared__ __align__(16) unsigned char lds[24576];
    const int t = threadIdx.x;
    const int lane = t & 63;
    const int w = t >> 6;
    const int lrow = lane & 15;
    const int lkb = (lane >> 4) << 3;
    const int lcq = (lane >> 4) << 2;
    const int btile = blockIdx.x & 7;     // 8 b-tiles of 64
    const int split = blockIdx.x >> 3;    // 64 v-splits
    const int b0 = btile * 64;

    f32x4 acc[2][4];
#pragma unroll
    for (int tr = 0; tr < 2; ++tr)
#pragma unroll
        for (int bt = 0; bt < 4; ++bt) acc[tr][bt] = (f32x4){0.f, 0.f, 0.f, 0.f};

    for (int ci = split; ci < 469; ci += 64) {
        const int v0 = ci * 64;
        __syncthreads();
        // stage phiT tile [128][64] (coalesced)
        for (int idx = t; idx < 1024; idx += 256) {
            int k = idx >> 3, v8 = (idx & 7) << 3;
            int vg = v0 + v8;
            short8 val;
            if (vg + 7 < NV) val = *(const short8*)&phiT[(size_t)k * NV + vg];
            else {
#pragma unroll
                for (int e = 0; e < 8; ++e)
                    ((unsigned short*)&val)[e] = (vg + e < NV) ? phiT[(size_t)k * NV + vg + e] : 0;
            }
            *(short8*)&lds[PH(k, v8)] = val;
        }
        // stage ratio tile [64][64] (coalesced)
        for (int idx = t; idx < 512; idx += 256) {
            int b = idx >> 3, v8 = (idx & 7) << 3;
            int vg = v0 + v8;
            short8 val;
            if (vg + 7 < NV) val = *(const short8*)&ratioT[(size_t)(b0 + b) * NV + vg];
            else {
#pragma unroll
                for (int e = 0; e < 8; ++e)
                    ((unsigned short*)&val)[e] = (vg + e < NV) ? ratioT[(size_t)(b0 + b) * NV + vg + e] : 0;
            }
            *(short8*)&lds[RT(b, v8)] = val;
        }
        __syncthreads();
#pragma unroll
        for (int ks = 0; ks < 2; ++ks) {
            short8 a0 = *(const short8*)&lds[PH(w * 32 + lrow,      ks * 32 + lkb)];
            short8 a1 = *(const short8*)&lds[PH(w * 32 + 16 + lrow, ks * 32 + lkb)];
#pragma unroll
            for (int bt = 0; bt < 4; ++bt) {
                short8 bb = *(const short8*)&lds[RT(bt * 16 + lrow, ks * 32 + lkb)];
                acc[0][bt] = __builtin_amdgcn_mfma_f32_16x16x32_bf16(a0, bb, acc[0][bt], 0, 0, 0);
                acc[1][bt] = __builtin_amdgcn_mfma_f32_16x16x32_bf16(a1, bb, acc[1][bt], 0, 0, 0);
            }
        }
    }
    float* dst = part + (size_t)split * 65536;
#pragma unroll
    for (int tr = 0; tr < 2; ++tr)
#pragma unroll
        for (int bt = 0; bt < 4; ++bt)
#pragma unroll
            for (int i = 0; i < 4; ++i) {
                int k = w * 32 + tr * 16 + lcq + i;
                int b = b0 + bt * 16 + lrow;
                dst[k * NB + b] = acc[tr][bt][i];
            }
}

// ---------------------------------------------------------------- layer0 finalize
__global__ __launch_bounds__(256) void k3_step(
    const float* __restrict__ phi0, const float* __restrict__ noise0,
    const float* __restrict__ NDot0, float* __restrict__ out,
    float* __restrict__ stepsum0)
{
    __shared__ float red[256];
    const int t = threadIdx.x;
    const int k = t & 127;
    const int base = blockIdx.x * 2048;
    float nd = NDot0[k];
    float inv_n = 1.f / fmaxf(nd, EPSF);
    float tmpsum = nd + 3000.f;
    float ssum = 0.f;
#pragma unroll
    for (int i = 0; i < 8; ++i) {
        int e = base + i * 256 + t;
        float phi = phi0[e], R = out[e], nz = noise0[e];
        float tmp = fmaf(100.f * phi, R, 0.1f);
        float step = phi + inv_n * (tmp - tmpsum * phi) + sqrtf(2.f * inv_n * phi) * nz;
        out[e] = step;
        ssum += step;
    }
    red[t] = ssum;
    __syncthreads();
    if (t < 128) atomicAdd(&stepsum0[k], red[t] + red[t + 128]);
}

__global__ __launch_bounds__(256) void k4_proj(
    const float* __restrict__ phi0, const float* __restrict__ stepsum0,
    float* __restrict__ out, float* __restrict__ psum0)
{
    __shared__ float red[256];
    const int t = threadIdx.x;
    const int k = t & 127;
    const int base = blockIdx.x * 2048;
    const float ss = stepsum0[k] - 1.f;
    float ps = 0.f;
#pragma unroll
    for (int i = 0; i < 8; ++i) {
        int e = base + i * 256 + t;
        float p = out[e] - ss * phi0[e];
        p = fmaxf(EPSF, p);
        out[e] = p;
        ps += p;
    }
    red[t] = ps;
    __syncthreads();
    if (t < 128) atomicAdd(&psum0[k], red[t] + red[t + 128]);
}

__global__ __launch_bounds__(256) void k5_norm(float* __restrict__ out,
                                               const float* __restrict__ psum0)
{
    const int t = threadIdx.x;
    const int k = t & 127;
    const int base = blockIdx.x * 2048;
    const float inv = 1.f / fmaxf(psum0[k], EPSF);
#pragma unroll
    for (int i = 0; i < 8; ++i) { int e = base + i * 256 + t; out[e] *= inv; }
}

// ---------------------------------------------------------------- layer1/2
// k6: fused partial-reduce (C0) + digamma ratio1
__global__ __launch_bounds__(256) void k6_ratio1(
    const float* __restrict__ phi1, const float* __restrict__ theta1,
    const float* __restrict__ theta0, const float* __restrict__ part,
    float* __restrict__ ratio1)
{
    int g = blockIdx.x * 256 + threadIdx.x;       // 128*512
    int d = g >> 9, b = g & 511;
    float c0 = 0.f;
    for (int s = 0; s < 64; ++s) c0 += part[(size_t)s * 65536 + g];
    float denom = 0.f;
    for (int k = 0; k < 64; ++k) denom = fmaf(phi1[d * 64 + k], theta1[k * NB + b], denom);
    denom = fmaxf(denom, EPSF);
    float xc = theta0[g] * c0;
    ratio1[g] = digammaf(denom + xc) - digammaf(denom);
}

__global__ __launch_bounds__(256) void k7_r1_w(
    const float* __restrict__ ratio1, const float* __restrict__ theta1,
    const float* __restrict__ phi1, float* __restrict__ R1, float* __restrict__ NDot1)
{
    int wid = (blockIdx.x * 256 + threadIdx.x) >> 6;  // 8192 waves: (d,k)
    int lane = threadIdx.x & 63;
    int d = wid >> 6, kk = wid & 63;
    float s = 0.f;
#pragma unroll
    for (int i = 0; i < 8; ++i) {
        int b = i * 64 + lane;
        s = fmaf(ratio1[d * NB + b], theta1[kk * NB + b], s);
    }
#pragma unroll
    for (int o = 1; o < 64; o <<= 1) s += __shfl_xor(s, o);
    if (lane == 0) {
        R1[wid] = s;
        atomicAdd(&NDot1[kk], 100.f * phi1[wid] * s);
    }
}

__global__ __launch_bounds__(256) void k8_x2(
    const float* __restrict__ phi1, const float* __restrict__ ratio1,
    const float* __restrict__ theta1, float* __restrict__ x2v)
{
    int g = blockIdx.x * 256 + threadIdx.x;       // 64*512
    int kk = g >> 9, b = g & 511;
    float s = 0.f;
    for (int d = 0; d < 128; ++d) s = fmaf(phi1[d * 64 + kk], ratio1[d * NB + b], s);
    x2v[g] = theta1[g] * s;
}

__global__ __launch_bounds__(256) void k10_ratio2(
    const float* __restrict__ phi2, const float* __restrict__ theta2,
    const float* __restrict__ x2v, float* __restrict__ ratio2)
{
    int g = blockIdx.x * 256 + threadIdx.x;       // 64*512
    int d = g >> 9, b = g & 511;
    float denom = 0.f;
    for (int k = 0; k < 32; ++k) denom = fmaf(phi2[d * 32 + k], theta2[k * NB + b], denom);
    denom = fmaxf(denom, EPSF);
    float xc = x2v[g];
    ratio2[g] = digammaf(denom + xc) - digammaf(denom);
}

__global__ __launch_bounds__(256) void k11_r2_w(
    const float* __restrict__ ratio2, const float* __restrict__ theta2,
    const float* __restrict__ phi2, float* __restrict__ R2, float* __restrict__ NDot2)
{
    int wid = (blockIdx.x * 256 + threadIdx.x) >> 6;  // 2048 waves: (d,k)
    int lane = threadIdx.x & 63;
    int d = wid >> 5, kk = wid & 31;
    float s = 0.f;
#pragma unroll
    for (int i = 0; i < 8; ++i) {
        int b = i * 64 + lane;
        s = fmaf(ratio2[d * NB + b], theta2[kk * NB + b], s);
    }
#pragma unroll
    for (int o = 1; o < 64; o <<= 1) s += __shfl_xor(s, o);
    if (lane == 0) {
        R2[wid] = s;
        atomicAdd(&NDot2[kk], 100.f * phi2[wid] * s);
    }
}

// one block per column k; blockDim = D (64 or 128)
__global__ void tlasgr_small(const float* __restrict__ phi, const float* __restrict__ R,
                             const float* __restrict__ noise, const float* __restrict__ NDot,
                             float* __restrict__ out, int K, float tmpadd)
{
    const int k = blockIdx.x;
    const int d = threadIdx.x;
    const int D = blockDim.x;
    const int e = d * K + k;
    __shared__ float red[4];
    float nd = NDot[k];
    float inv_n = 1.f / fmaxf(nd, EPSF);
    float tmpsum = nd + tmpadd;
    float phiv = phi[e];
    float tmp = fmaf(100.f * phiv, R[e], 0.1f);
    float step = phiv + inv_n * (tmp - tmpsum * phiv) + sqrtf(2.f * inv_n * phiv) * noise[e];
    float s = step;
#pragma unroll
    for (int o = 1; o < 64; o <<= 1) s += __shfl_xor(s, o);
    if ((d & 63) == 0) red[d >> 6] = s;
    __syncthreads();
    float ssum = (D > 64) ? (red[0] + red[1]) : red[0];
    float p = fmaxf(EPSF, step - (ssum - 1.f) * phiv);
    float q = p;
#pragma unroll
    for (int o = 1; o < 64; o <<= 1) q += __shfl_xor(q, o);
    if ((d & 63) == 0) red[2 + (d >> 6)] = q;
    __syncthreads();
    float psum = (D > 64) ? (red[2] + red[3]) : red[2];
    out[e] = p / fmaxf(psum, EPSF);
}

// ----------------------------------------------------------------
extern "C" void kernel_launch(void* const* d_in, const int* in_sizes, int n_in,
                              void* d_out, int out_size, void* d_ws, size_t ws_size,
                              hipStream_t stream)
{
    const float* x      = (const float*)d_in[0];
    const float* theta0 = (const float*)d_in[1];
    const float* theta1 = (const float*)d_in[2];
    const float* theta2 = (const float*)d_in[3];
    const float* phi0   = (const float*)d_in[4];
    const float* phi1   = (const float*)d_in[5];
    const float* phi2   = (const float*)d_in[6];
    const float* noise0 = (const float*)d_in[7];
    const float* noise1 = (const float*)d_in[8];
    const float* noise2 = (const float*)d_in[9];
    float* out = (float*)d_out;
    float* ws  = (float*)d_ws;

    unsigned short* ratioT = (unsigned short*)ws;              // (512,30000) bf16
    unsigned short* phiT   = (unsigned short*)(ws + 7680000);  // (128,30000) bf16
    unsigned short* thT_bf = (unsigned short*)(ws + 9600000);  // (512,128) bf16
    unsigned short* th_bf  = (unsigned short*)(ws + 9632768);  // (128,512) bf16
    float* part     = ws + 9665536;       // 64*65536 = 4,194,304
    float* NDot0    = ws + 13859840;      // 128
    float* stepsum0 = ws + 13859968;      // 128
    float* psum0    = ws + 13860096;      // 128
    float* NDot1    = ws + 13860224;      // 64
    float* NDot2    = ws + 13860288;      // 32
    float* ratio1   = ws + 13860320;      // 65,536
    float* R1       = ws + 13925856;      // 8,192
    float* x2v      = ws + 13934048;      // 32,768
    float* ratio2   = ws + 13966816;      // 32,768
    float* R2       = ws + 13999584;      // 2,048 -> end 14,001,632 floats (56 MB)

    // zero atomic accumulators (NDot0..NDot2, contiguous 480 floats)
    hipMemsetAsync(NDot0, 0, 480 * sizeof(float), stream);

    pk_theta<<<64, 256, 0, stream>>>(theta0, th_bf, thT_bf);

    // layer 0: R0 lives in d_out[0..3,840,000) transformed in place
    k1_mfma<<<938, 256, 0, stream>>>(x, phi0, thT_bf, th_bf, ratioT, phiT, out, NDot0);
    k2_mfma<<<512, 256, 0, stream>>>(phiT, ratioT, part);
    k3_step<<<1875, 256, 0, stream>>>(phi0, noise0, NDot0, out, stepsum0);
    k4_proj<<<1875, 256, 0, stream>>>(phi0, stepsum0, out, psum0);
    k5_norm<<<1875, 256, 0, stream>>>(out, psum0);

    // layer 1
    k6_ratio1<<<256, 256, 0, stream>>>(phi1, theta1, theta0, part, ratio1);
    k7_r1_w<<<2048, 256, 0, stream>>>(ratio1, theta1, phi1, R1, NDot1);
    k8_x2<<<128, 256, 0, stream>>>(phi1, ratio1, theta1, x2v);
    tlasgr_small<<<64, 128, 0, stream>>>(phi1, R1, noise1, NDot1, out + 3840000, 64, 12.8f);

    // layer 2
    k10_ratio2<<<128, 256, 0, stream>>>(phi2, theta2, x2v, ratio2);
    k11_r2_w<<<512, 256, 0, stream>>>(ratio2, theta2, phi2, R2, NDot2);
    tlasgr_small<<<32, 64, 0, stream>>>(phi2, R2, noise2, NDot2, out + 3848192, 32, 6.4f);
}

// Round 4
// 258.176 us; speedup vs baseline: 1.3745x; 1.3745x over previous
//
#include <hip/hip_runtime.h>
#include <math.h>

#define EPSF 2.2e-10f
#define NV 30000
#define NB 512

typedef __attribute__((ext_vector_type(8))) short short8;
typedef __attribute__((ext_vector_type(4))) float f32x4;
typedef __attribute__((ext_vector_type(4))) unsigned short ushort4v;

__device__ __forceinline__ unsigned short f2bf(float f) {
    unsigned int u = __float_as_uint(f);
    u += 0x7fffu + ((u >> 16) & 1u);
    return (unsigned short)(u >> 16);
}
__device__ __forceinline__ float bf2f(unsigned short h) {
    return __uint_as_float((unsigned int)h << 16);
}

// ---------------------------------------------------------------- digamma
__device__ __forceinline__ float digammaf(float xx) {
    float x = xx, r = 0.f;
    while (x < 6.f) { r -= 1.f / x; x += 1.f; }
    float f = 1.f / (x * x);
    float s = logf(x) - 0.5f / x
        - f * (0.0833333333f - f * (0.0083333333f - f * (0.0039682540f
        - f * (0.0041666667f - f * 0.0075757576f))));
    return r + s;
}

// ================================================================ pk_theta
__global__ __launch_bounds__(256) void pk_theta(
    const float* __restrict__ th, unsigned short* __restrict__ th_bf,
    unsigned short* __restrict__ thT_bf)
{
    int idx = blockIdx.x * 256 + threadIdx.x;   // 16384 threads
    int k = idx >> 7, b4 = (idx & 127) << 2;
    float4 v = *(const float4*)&th[k * NB + b4];
    ushort4v h = { f2bf(v.x), f2bf(v.y), f2bf(v.z), f2bf(v.w) };
    *(ushort4v*)&th_bf[k * NB + b4] = h;
#pragma unroll
    for (int i = 0; i < 4; ++i) thT_bf[(b4 + i) * 128 + k] = h[i];
}

// ================================================================ k1 (MFMA, barrier-free main loop)
// Block = 32 v-rows; wave w owns b-slice [w*128, w*128+128) for the whole block.
//   denomT(b,v) = thetaT(b,:)@phiT(:,v)   (A from L2-hot thT_bf)
//   ratioT(b,v) = x/denom -> bf16 -> global + WAVE-PRIVATE LDS (no barrier)
//   R0T(k,v)   += theta(k,:)@ratioT(:,v)  (A from L2-hot th_bf, 64-VGPR acc)
// Epilogue: 4-pass cross-wave reduce, R0 writeout, NDot0 / Sum(phi) / Sum(sqrt(phi)*nz) atomics.
#define K1_PHI(v,k)    ((((v) << 8) + ((k) << 1)) ^ (((v) & 7) << 4))
#define K1_RAT(wb,v,b) ((wb) + ((((v) << 6) + ((b) << 1)) ^ (((v) & 7) << 4)))
#define K1_R0(v,k)     (16384 + ((((v) << 9) + ((k) << 2)) ^ (((v) & 7) << 4)))

__global__ __launch_bounds__(256, 4) void k1_mfma(
    const float* __restrict__ x,               // (B,V)
    const float* __restrict__ phi0,            // (V,128)
    const unsigned short* __restrict__ thT_bf, // (512,128)
    const unsigned short* __restrict__ th_bf,  // (128,512)
    const float* __restrict__ noise0,          // (V,128)
    unsigned short* __restrict__ ratioT,       // (B,V) bf16
    unsigned short* __restrict__ phiT,         // (128,V) bf16
    float* __restrict__ R0,                    // (V,128) = d_out region
    float* __restrict__ NDot0,                 // (128)
    float* __restrict__ Sphi,                  // (128)
    float* __restrict__ Snz)                   // (128)
{
    __shared__ __align__(16) unsigned char lds[32768];
    const int t = threadIdx.x, lane = t & 63, w = t >> 6;
    const int lrow = lane & 15, hi = lane >> 4;
    const int lkb = hi << 3, lcq = hi << 2;
    const int vbase = blockIdx.x << 5;

    // stage phi (32 v-rows) -> bf16 LDS
    for (int idx = t; idx < 512; idx += 256) {
        int v = idx >> 4, kc = (idx & 15) << 3;
        int vg = vbase + v;
        float4 a = {0,0,0,0}, b = {0,0,0,0};
        if (vg < NV) {
            a = *(const float4*)&phi0[(size_t)vg * 128 + kc];
            b = *(const float4*)&phi0[(size_t)vg * 128 + kc + 4];
        }
        ushort4v h0 = { f2bf(a.x), f2bf(a.y), f2bf(a.z), f2bf(a.w) };
        ushort4v h1 = { f2bf(b.x), f2bf(b.y), f2bf(b.z), f2bf(b.w) };
        *(ushort4v*)&lds[K1_PHI(v, kc)]     = h0;
        *(ushort4v*)&lds[K1_PHI(v, kc + 4)] = h1;
    }
    __syncthreads();
    // phiT writeout (for k2)
    for (int idx = t; idx < 4096; idx += 256) {
        int v = idx & 31, k = idx >> 5, vg = vbase + v;
        if (vg < NV)
            phiT[(size_t)k * NV + vg] = *(const unsigned short*)&lds[K1_PHI(v, k)];
    }

    f32x4 acc[8][2];
#pragma unroll
    for (int kg = 0; kg < 8; ++kg)
#pragma unroll
        for (int vg = 0; vg < 2; ++vg) acc[kg][vg] = (f32x4){0.f, 0.f, 0.f, 0.f};

    const int wb = 8192 + (w << 11);   // wave-private 2KB rat region
    const int bw = w << 7;             // wave b-base

    for (int bp = 0; bp < 4; ++bp) {
        const int b32 = bw + (bp << 5);
#pragma unroll
        for (int bg = 0; bg < 2; ++bg) {
            const int bb = b32 + (bg << 4);
            short8 at4[4];
#pragma unroll
            for (int ks = 0; ks < 4; ++ks)
                at4[ks] = *(const short8*)&thT_bf[(size_t)(bb + lrow) * 128 + (ks << 5) + lkb];
            f32x4 dacc[2];
            dacc[0] = (f32x4){0.f,0.f,0.f,0.f}; dacc[1] = (f32x4){0.f,0.f,0.f,0.f};
#pragma unroll
            for (int ks = 0; ks < 4; ++ks)
#pragma unroll
                for (int vg = 0; vg < 2; ++vg) {
                    short8 bf = *(const short8*)&lds[K1_PHI(vg * 16 + lrow, (ks << 5) + lkb)];
                    dacc[vg] = __builtin_amdgcn_mfma_f32_16x16x32_bf16(at4[ks], bf, dacc[vg], 0, 0, 0);
                }
#pragma unroll
            for (int vg = 0; vg < 2; ++vg) {
                const int vloc = vg * 16 + lrow;
                const int vg_g = vbase + vloc;
                ushort4v h;
#pragma unroll
                for (int i = 0; i < 4; ++i) {
                    float den = fmaxf(dacc[vg][i], EPSF);
                    float xval = (vg_g < NV) ? x[(size_t)(bb + lcq + i) * NV + vg_g] : 0.f;
                    float r = xval * __builtin_amdgcn_rcpf(den);
                    h[i] = f2bf(r);
                    if (vg_g < NV) ratioT[(size_t)(bb + lcq + i) * NV + vg_g] = h[i];
                }
                *(ushort4v*)&lds[K1_RAT(wb, vloc, (bg << 4) + lcq)] = h;
            }
        }
        // R0T accumulate over this 32-b pair (wave-private LDS read; waitcnt only)
        short8 brat[2];
#pragma unroll
        for (int vg = 0; vg < 2; ++vg)
            brat[vg] = *(const short8*)&lds[K1_RAT(wb, vg * 16 + lrow, lkb)];
#pragma unroll
        for (int kg = 0; kg < 8; ++kg) {
            short8 ak = *(const short8*)&th_bf[(size_t)(kg * 16 + lrow) * NB + b32 + lkb];
#pragma unroll
            for (int vg = 0; vg < 2; ++vg)
                acc[kg][vg] = __builtin_amdgcn_mfma_f32_16x16x32_bf16(ak, brat[vg], acc[kg][vg], 0, 0, 0);
        }
    }

    // cross-wave reduction of R0 partials (4 passes)
    for (int p = 0; p < 4; ++p) {
        if (w == p) {
#pragma unroll
            for (int kg = 0; kg < 8; ++kg)
#pragma unroll
                for (int vg = 0; vg < 2; ++vg) {
                    const int ad = K1_R0(vg * 16 + lrow, (kg << 4) + lcq);
                    f32x4 val = acc[kg][vg];
                    if (p) val += *(const f32x4*)&lds[ad];
                    *(f32x4*)&lds[ad] = val;
                }
        }
        __syncthreads();
    }

    // writeout + NDot0 + Sphi + Snz
    const int kf = t & 127, vh = t >> 7;
    float nd = 0.f, sp = 0.f, sn = 0.f;
#pragma unroll
    for (int vi = 0; vi < 16; ++vi) {
        int v = (vh << 4) + vi;
        int vg = vbase + v;
        if (vg < NV) {
            float r0v = *(const float*)&lds[K1_R0(v, kf)];
            float ph  = bf2f(*(const unsigned short*)&lds[K1_PHI(v, kf)]);
            R0[(size_t)vg * 128 + kf] = r0v;
            nd += ph * r0v;
            sp += ph;
            sn += sqrtf(ph) * noise0[(size_t)vg * 128 + kf];
        }
    }
    float* red = (float*)&lds[8192];
    red[t] = nd; red[256 + t] = sp; red[512 + t] = sn;
    __syncthreads();
    if (t < 128) {
        atomicAdd(&NDot0[t], 100.f * (red[t] + red[t + 128]));
        atomicAdd(&Sphi[t],  red[256 + t] + red[384 + t]);
        atomicAdd(&Snz[t],   red[512 + t] + red[640 + t]);
    }
}

// ================================================================ k2 (MFMA)
// part[split](k,b) = sum_{v in split} phiT(k,v)*ratio(v,b); 8 b-tiles x 80 splits
#define K2_PH(k,v) ((((k) << 7) + ((v) << 1)) ^ (((k) & 7) << 4))
#define K2_RT(b,v) ((16384 + ((b) << 7) + ((v) << 1)) ^ (((b) & 7) << 4))

__global__ __launch_bounds__(256, 4) void k2_mfma(
    const unsigned short* __restrict__ phiT,   // (128,V) bf16
    const unsigned short* __restrict__ ratioT, // (B,V) bf16
    float* __restrict__ part)                  // (80,128,512)
{
    __shared__ __align__(16) unsigned char lds[24576];
    const int t = threadIdx.x, lane = t & 63, w = t >> 6;
    const int lrow = lane & 15, hi = lane >> 4;
    const int lkb = hi << 3, lcq = hi << 2;
    const int btile = blockIdx.x & 7;     // 8 b-tiles of 64
    const int split = blockIdx.x >> 3;    // 80 splits
    const int b0 = btile << 6;

    f32x4 acc[2][4];
#pragma unroll
    for (int tr = 0; tr < 2; ++tr)
#pragma unroll
        for (int bt = 0; bt < 4; ++bt) acc[tr][bt] = (f32x4){0.f, 0.f, 0.f, 0.f};

    for (int ci = split; ci < 469; ci += 80) {
        const int v0 = ci << 6;
        __syncthreads();
        for (int idx = t; idx < 1024; idx += 256) {      // phiT tile 128x64
            int k = idx >> 3, v8 = (idx & 7) << 3, vg = v0 + v8;
            short8 val;
            if (vg + 7 < NV) val = *(const short8*)&phiT[(size_t)k * NV + vg];
            else {
#pragma unroll
                for (int e = 0; e < 8; ++e)
                    ((unsigned short*)&val)[e] = (vg + e < NV) ? phiT[(size_t)k * NV + vg + e] : 0;
            }
            *(short8*)&lds[K2_PH(k, v8)] = val;
        }
        for (int idx = t; idx < 512; idx += 256) {       // ratio tile 64x64
            int b = idx >> 3, v8 = (idx & 7) << 3, vg = v0 + v8;
            short8 val;
            if (vg + 7 < NV) val = *(const short8*)&ratioT[(size_t)(b0 + b) * NV + vg];
            else {
#pragma unroll
                for (int e = 0; e < 8; ++e)
                    ((unsigned short*)&val)[e] = (vg + e < NV) ? ratioT[(size_t)(b0 + b) * NV + vg + e] : 0;
            }
            *(short8*)&lds[K2_RT(b, v8)] = val;
        }
        __syncthreads();
#pragma unroll
        for (int vs = 0; vs < 2; ++vs) {
            short8 a0 = *(const short8*)&lds[K2_PH(w * 32 + lrow,      (vs << 5) + lkb)];
            short8 a1 = *(const short8*)&lds[K2_PH(w * 32 + 16 + lrow, (vs << 5) + lkb)];
#pragma unroll
            for (int bt = 0; bt < 4; ++bt) {
                short8 bb = *(const short8*)&lds[K2_RT(bt * 16 + lrow, (vs << 5) + lkb)];
                acc[0][bt] = __builtin_amdgcn_mfma_f32_16x16x32_bf16(a0, bb, acc[0][bt], 0, 0, 0);
                acc[1][bt] = __builtin_amdgcn_mfma_f32_16x16x32_bf16(a1, bb, acc[1][bt], 0, 0, 0);
            }
        }
    }
    float* dst = part + (size_t)split * 65536;
#pragma unroll
    for (int tr = 0; tr < 2; ++tr)
#pragma unroll
        for (int bt = 0; bt < 4; ++bt)
#pragma unroll
            for (int i = 0; i < 4; ++i)
                dst[(w * 32 + tr * 16 + lcq + i) * NB + b0 + bt * 16 + lrow] = acc[tr][bt][i];
}

// ---------------------------------------------------------------- k34: fused step+proj
// stepsum computed analytically: stepsum = Sphi + inv_n*tmpsum*(1-Sphi) + sqrt(2*inv_n)*Snz
__global__ __launch_bounds__(256) void k34(
    const float* __restrict__ phi0, const float* __restrict__ noise0,
    const float* __restrict__ NDot0, const float* __restrict__ Sphi,
    const float* __restrict__ Snz,
    float* __restrict__ out /* holds R0 -> p */, float* __restrict__ psum0)
{
    __shared__ float red[256];
    const int t = threadIdx.x;
    const int k = t & 127;
    const size_t base = (size_t)blockIdx.x * 2048;
    float ndv = NDot0[k];
    float inv_n = 1.f / fmaxf(ndv, EPSF);
    float tmpsum = ndv + 3000.f;
    float sp = Sphi[k], sn = Snz[k];
    float stepsum = sp + inv_n * tmpsum * (1.f - sp) + sqrtf(2.f * inv_n) * sn;
    float ssm1 = stepsum - 1.f;
    float ps = 0.f;
#pragma unroll
    for (int i = 0; i < 8; ++i) {
        size_t e = base + i * 256 + t;
        float phi = phi0[e], R = out[e], nz = noise0[e];
        float tmp = fmaf(100.f * phi, R, 0.1f);
        float step = phi + inv_n * (tmp - tmpsum * phi) + sqrtf(2.f * inv_n * phi) * nz;
        float p = fmaxf(EPSF, step - ssm1 * phi);
        out[e] = p;
        ps += p;
    }
    red[t] = ps;
    __syncthreads();
    if (t < 128) atomicAdd(&psum0[k], red[t] + red[t + 128]);
}

__global__ __launch_bounds__(256) void k5_norm(float* __restrict__ out,
                                               const float* __restrict__ psum0)
{
    const int t = threadIdx.x;
    const int k = t & 127;
    const size_t base = (size_t)blockIdx.x * 2048;
    const float inv = 1.f / fmaxf(psum0[k], EPSF);
#pragma unroll
    for (int i = 0; i < 8; ++i) { size_t e = base + i * 256 + t; out[e] *= inv; }
}

// ---------------------------------------------------------------- layer1/2
__global__ __launch_bounds__(256) void k6_ratio1(
    const float* __restrict__ phi1, const float* __restrict__ theta1,
    const float* __restrict__ theta0, const float* __restrict__ part,
    float* __restrict__ ratio1)
{
    int g = blockIdx.x * 256 + threadIdx.x;       // 128*512
    int d = g >> 9, b = g & 511;
    float c0a = 0.f, c0b = 0.f, c0c = 0.f, c0d = 0.f;
    for (int s = 0; s < 80; s += 4) {
        c0a += part[(size_t)s * 65536 + g];
        c0b += part[(size_t)(s + 1) * 65536 + g];
        c0c += part[(size_t)(s + 2) * 65536 + g];
        c0d += part[(size_t)(s + 3) * 65536 + g];
    }
    float c0 = (c0a + c0b) + (c0c + c0d);
    float denom = 0.f;
    for (int k = 0; k < 64; ++k) denom = fmaf(phi1[d * 64 + k], theta1[k * NB + b], denom);
    denom = fmaxf(denom, EPSF);
    float xc = theta0[g] * c0;
    ratio1[g] = digammaf(denom + xc) - digammaf(denom);
}

// k7 (blocks 0..2047) + k8 (blocks 2048..2175) merged
__global__ __launch_bounds__(256) void k78(
    const float* __restrict__ ratio1, const float* __restrict__ theta1,
    const float* __restrict__ phi1, float* __restrict__ R1,
    float* __restrict__ NDot1, float* __restrict__ x2v)
{
    if (blockIdx.x < 2048) {
        int wid = (blockIdx.x * 256 + threadIdx.x) >> 6;  // 8192 waves: (d,k)
        int lane = threadIdx.x & 63;
        int d = wid >> 6, kk = wid & 63;
        float s = 0.f;
#pragma unroll
        for (int i = 0; i < 8; ++i) {
            int b = i * 64 + lane;
            s = fmaf(ratio1[d * NB + b], theta1[kk * NB + b], s);
        }
#pragma unroll
        for (int o = 1; o < 64; o <<= 1) s += __shfl_xor(s, o);
        if (lane == 0) {
            R1[wid] = s;
            atomicAdd(&NDot1[kk], 100.f * phi1[wid] * s);
        }
    } else {
        int g = (blockIdx.x - 2048) * 256 + threadIdx.x;  // 64*512
        int kk = g >> 9, b = g & 511;
        float s = 0.f;
        for (int d = 0; d < 128; ++d) s = fmaf(phi1[d * 64 + kk], ratio1[d * NB + b], s);
        x2v[g] = theta1[g] * s;
    }
}

// k10 (blocks 0..127) + tlasgr layer1 (blocks 128..159, 2 columns per block)
__global__ __launch_bounds__(256) void k10t1(
    const float* __restrict__ phi2, const float* __restrict__ theta2,
    const float* __restrict__ x2v, float* __restrict__ ratio2,
    const float* __restrict__ phi1, const float* __restrict__ R1,
    const float* __restrict__ noise1, const float* __restrict__ NDot1,
    float* __restrict__ out1)
{
    __shared__ float red[8];
    if (blockIdx.x < 128) {
        int g = blockIdx.x * 256 + threadIdx.x;       // 64*512
        int d = g >> 9, b = g & 511;
        float denom = 0.f;
        for (int k = 0; k < 32; ++k) denom = fmaf(phi2[d * 32 + k], theta2[k * NB + b], denom);
        denom = fmaxf(denom, EPSF);
        float xc = x2v[g];
        ratio2[g] = digammaf(denom + xc) - digammaf(denom);
    } else {
        const int t = threadIdx.x;
        const int c = t >> 7;                          // 0/1
        const int k = (blockIdx.x - 128) * 2 + c;
        const int d = t & 127;
        const int e = d * 64 + k;
        float ndv = NDot1[k];
        float inv_n = 1.f / fmaxf(ndv, EPSF);
        float tmpsum = ndv + 12.8f;
        float phiv = phi1[e];
        float tmp = fmaf(100.f * phiv, R1[e], 0.1f);
        float step = phiv + inv_n * (tmp - tmpsum * phiv) + sqrtf(2.f * inv_n * phiv) * noise1[e];
        float s = step;
#pragma unroll
        for (int o = 1; o < 64; o <<= 1) s += __shfl_xor(s, o);
        int slot = t >> 6;
        if ((t & 63) == 0) red[slot] = s;
        __syncthreads();
        float ssum = red[c * 2] + red[c * 2 + 1];
        float p = fmaxf(EPSF, step - (ssum - 1.f) * phiv);
        float q = p;
#pragma unroll
        for (int o = 1; o < 64; o <<= 1) q += __shfl_xor(q, o);
        if ((t & 63) == 0) red[4 + slot] = q;
        __syncthreads();
        float psum = red[4 + c * 2] + red[4 + c * 2 + 1];
        out1[e] = p / fmaxf(psum, EPSF);
    }
}

__global__ __launch_bounds__(256) void k11_r2_w(
    const float* __restrict__ ratio2, const float* __restrict__ theta2,
    const float* __restrict__ phi2, float* __restrict__ R2, float* __restrict__ NDot2)
{
    int wid = (blockIdx.x * 256 + threadIdx.x) >> 6;  // 2048 waves: (d,k)
    int lane = threadIdx.x & 63;
    int d = wid >> 5, kk = wid & 31;
    float s = 0.f;
#pragma unroll
    for (int i = 0; i < 8; ++i) {
        int b = i * 64 + lane;
        s = fmaf(ratio2[d * NB + b], theta2[kk * NB + b], s);
    }
#pragma unroll
    for (int o = 1; o < 64; o <<= 1) s += __shfl_xor(s, o);
    if (lane == 0) {
        R2[wid] = s;
        atomicAdd(&NDot2[kk], 100.f * phi2[wid] * s);
    }
}

// layer2 tlasgr: 4 columns per block (one wave each), D=64
__global__ __launch_bounds__(256) void t2_quad(
    const float* __restrict__ phi2, const float* __restrict__ R2,
    const float* __restrict__ noise2, const float* __restrict__ NDot2,
    float* __restrict__ out2)
{
    const int c = blockIdx.x * 4 + (threadIdx.x >> 6);
    const int d = threadIdx.x & 63;
    const int e = d * 32 + c;
    float ndv = NDot2[c];
    float inv_n = 1.f / fmaxf(ndv, EPSF);
    float tmpsum = ndv + 6.4f;
    float phiv = phi2[e];
    float tmp = fmaf(100.f * phiv, R2[e], 0.1f);
    float step = phiv + inv_n * (tmp - tmpsum * phiv) + sqrtf(2.f * inv_n * phiv) * noise2[e];
    float s = step;
#pragma unroll
    for (int o = 1; o < 64; o <<= 1) s += __shfl_xor(s, o);
    float p = fmaxf(EPSF, step - (s - 1.f) * phiv);
    float q = p;
#pragma unroll
    for (int o = 1; o < 64; o <<= 1) q += __shfl_xor(q, o);
    out2[e] = p / fmaxf(q, EPSF);
}

// ----------------------------------------------------------------
extern "C" void kernel_launch(void* const* d_in, const int* in_sizes, int n_in,
                              void* d_out, int out_size, void* d_ws, size_t ws_size,
                              hipStream_t stream)
{
    const float* x      = (const float*)d_in[0];
    const float* theta0 = (const float*)d_in[1];
    const float* theta1 = (const float*)d_in[2];
    const float* theta2 = (const float*)d_in[3];
    const float* phi0   = (const float*)d_in[4];
    const float* phi1   = (const float*)d_in[5];
    const float* phi2   = (const float*)d_in[6];
    const float* noise0 = (const float*)d_in[7];
    const float* noise1 = (const float*)d_in[8];
    const float* noise2 = (const float*)d_in[9];
    float* out = (float*)d_out;
    float* ws  = (float*)d_ws;

    unsigned short* ratioT = (unsigned short*)ws;              // (512,30000) bf16
    unsigned short* phiT   = (unsigned short*)(ws + 7680000);  // (128,30000) bf16
    unsigned short* thT_bf = (unsigned short*)(ws + 9600000);  // (512,128)
    unsigned short* th_bf  = (unsigned short*)(ws + 9632768);  // (128,512)
    float* part     = ws + 9665536;       // 80*65536 = 5,242,880
    float* NDot0    = ws + 14908416;      // 128 (zeroed)
    float* Sphi     = ws + 14908544;      // 128 (zeroed)
    float* Snz      = ws + 14908672;      // 128 (zeroed)
    float* psum0    = ws + 14908800;      // 128 (zeroed)
    float* NDot1    = ws + 14908928;      // 64  (zeroed)
    float* NDot2    = ws + 14908992;      // 32  (zeroed)
    float* ratio1   = ws + 14909024;      // 65,536
    float* R1       = ws + 14974560;      // 8,192
    float* x2v      = ws + 14982752;      // 32,768
    float* ratio2   = ws + 15015520;      // 32,768
    float* R2       = ws + 15048288;      // 2,048  -> end 15,050,336 floats (60.2 MB)

    hipMemsetAsync(NDot0, 0, 608 * sizeof(float), stream);

    pk_theta<<<64, 256, 0, stream>>>(theta0, th_bf, thT_bf);

    // layer 0: R0 in d_out[0..3,840,000), transformed in place
    k1_mfma<<<938, 256, 0, stream>>>(x, phi0, thT_bf, th_bf, noise0,
                                     ratioT, phiT, out, NDot0, Sphi, Snz);
    k2_mfma<<<640, 256, 0, stream>>>(phiT, ratioT, part);
    k34<<<1875, 256, 0, stream>>>(phi0, noise0, NDot0, Sphi, Snz, out, psum0);
    k5_norm<<<1875, 256, 0, stream>>>(out, psum0);

    // layer 1
    k6_ratio1<<<256, 256, 0, stream>>>(phi1, theta1, theta0, part, ratio1);
    k78<<<2176, 256, 0, stream>>>(ratio1, theta1, phi1, R1, NDot1, x2v);
    k10t1<<<160, 256, 0, stream>>>(phi2, theta2, x2v, ratio2,
                                   phi1, R1, noise1, NDot1, out + 3840000);

    // layer 2
    k11_r2_w<<<512, 256, 0, stream>>>(ratio2, theta2, phi2, R2, NDot2);
    t2_quad<<<8, 256, 0, stream>>>(phi2, R2, noise2, NDot2, out + 3848192);
}